// Round 2
// baseline (360.058 us; speedup 1.0000x reference)
//
#include <hip/hip_runtime.h>
#include <cfloat>

// TopKPooling: per (b, d) channel, top-8 over L with monotone padding mask.
// x: (B=32, L=8192, D=256) f32, x_mask: (B, L) i32 (1 = padded, monotone 0->1)
// out: (B, 8*D) f32, out[b][k*D + d] = k-th largest of valid x[b][:,d].
//
// R2 changes vs R1 (theory: ~100us of kernel time, 3x over roofline, from
// scratch-spill risk of float r[8] + single dep chain + scalar loads):
//  - Top8 = named scalar fields (no array -> guaranteed registers).
//  - float4 loads: lane owns 4 channels -> 4 independent insert chains (ILP)
//    and 1 KB/wave per load instruction.
//  - 1 wave = 1 chunk of CL=64 rows; masked chunks write NOTHING; pass2
//    binary-searches the mask and reads only valid chunks' lists.

#define TOPK 8
#define BB 32
#define LL 8192
#define DD 256
#define CL 64           // L-rows per wave-chunk
#define NC (LL / CL)    // 128 chunks per batch row

struct Top8 { float r0, r1, r2, r3, r4, r5, r6, r7; };

#define CMPX(a, b) { float _hi = fmaxf(a, b); float _lo = fminf(a, b); (a) = _hi; (b) = _lo; }

__device__ __forceinline__ void t8_init(Top8& t) {
    t.r0 = t.r1 = t.r2 = t.r3 = t.r4 = t.r5 = t.r6 = t.r7 = -FLT_MAX;
}

// r0>=r1>=...>=r7 descending. One max + 7 compare-exchanges, branchless.
__device__ __forceinline__ void t8_ins(Top8& t, float v) {
    t.r7 = fmaxf(t.r7, v);
    CMPX(t.r6, t.r7); CMPX(t.r5, t.r6); CMPX(t.r4, t.r5); CMPX(t.r3, t.r4);
    CMPX(t.r2, t.r3); CMPX(t.r1, t.r2); CMPX(t.r0, t.r1);
}

// first index where mrow[i] != 0, assuming monotone 0->1; returns hi0 if none
__device__ __forceinline__ int mask_lower_bound(const int* mrow, int lo0, int hi0) {
    int lo = lo0, hi = hi0;
    while (lo < hi) {
        int mid = (lo + hi) >> 1;
        if (mrow[mid]) hi = mid; else lo = mid + 1;
    }
    return lo;
}

__global__ __launch_bounds__(256, 4) void topk_pass1(
    const float* __restrict__ x, const int* __restrict__ mask,
    float* __restrict__ ws) {
    const int b = blockIdx.x;
    const int lane = threadIdx.x & 63;
    const int wv = threadIdx.x >> 6;            // 0..3
    const int chunk = blockIdx.y * 4 + wv;      // 0..127
    const int l0 = chunk * CL;
    const int* mrow = mask + b * LL;

    if (mrow[l0]) return;   // fully padded chunk: pass2 will not read its slot

    int nvalid;
    if (!mrow[l0 + CL - 1]) {
        nvalid = CL;
    } else {
        nvalid = mask_lower_bound(mrow, l0 + 1, l0 + CL - 1) - l0;  // >=1
    }

    Top8 t0, t1, t2, t3;
    t8_init(t0); t8_init(t1); t8_init(t2); t8_init(t3);

    // lane owns channels lane*4 .. lane*4+3; row stride = 64 float4s
    const float4* xp = (const float4*)(x + ((size_t)b * LL + l0) * DD) + lane;
    float4 v = xp[0];
    for (int l = 1; l < nvalid; ++l) {
        float4 nv = xp[(size_t)l * (DD / 4)];   // prefetch next row
        t8_ins(t0, v.x); t8_ins(t1, v.y); t8_ins(t2, v.z); t8_ins(t3, v.w);
        v = nv;
    }
    t8_ins(t0, v.x); t8_ins(t1, v.y); t8_ins(t2, v.z); t8_ins(t3, v.w);

    // ws[b][chunk][k][ch]: per k, lanes store float4 at consecutive channels
    float4* wp = (float4*)(ws + ((size_t)(b * NC + chunk) * TOPK) * DD) + lane;
    wp[0 * (DD / 4)] = make_float4(t0.r0, t1.r0, t2.r0, t3.r0);
    wp[1 * (DD / 4)] = make_float4(t0.r1, t1.r1, t2.r1, t3.r1);
    wp[2 * (DD / 4)] = make_float4(t0.r2, t1.r2, t2.r2, t3.r2);
    wp[3 * (DD / 4)] = make_float4(t0.r3, t1.r3, t2.r3, t3.r3);
    wp[4 * (DD / 4)] = make_float4(t0.r4, t1.r4, t2.r4, t3.r4);
    wp[5 * (DD / 4)] = make_float4(t0.r5, t1.r5, t2.r5, t3.r5);
    wp[6 * (DD / 4)] = make_float4(t0.r6, t1.r6, t2.r6, t3.r6);
    wp[7 * (DD / 4)] = make_float4(t0.r7, t1.r7, t2.r7, t3.r7);
}

__global__ __launch_bounds__(512) void topk_pass2(
    const float* __restrict__ ws, const int* __restrict__ mask,
    float* __restrict__ out) {
    __shared__ float lds[8 * TOPK * 64];        // 16 KB
    const int b = blockIdx.x;
    const int q = blockIdx.y;                   // channel group 0..3
    const int c = threadIdx.x & 63;
    const int ps = threadIdx.x >> 6;            // 0..7 list-split groups
    const int d = q * 64 + c;
    const int* mrow = mask + b * LL;

    // length of valid region (uniform across block; lengths >= 8 guaranteed)
    const int len = mask_lower_bound(mrow, 0, LL);
    const int nvc = (len + CL - 1) / CL;        // chunks actually written

    Top8 t;
    t8_init(t);
    for (int j = ps; j < nvc; j += 8) {
        const float* wp = ws + ((size_t)(b * NC + j) * TOPK) * DD + d;
        t8_ins(t, wp[0 * DD]); t8_ins(t, wp[1 * DD]);
        t8_ins(t, wp[2 * DD]); t8_ins(t, wp[3 * DD]);
        t8_ins(t, wp[4 * DD]); t8_ins(t, wp[5 * DD]);
        t8_ins(t, wp[6 * DD]); t8_ins(t, wp[7 * DD]);
    }

    float* lp = lds + ps * TOPK * 64 + c;
    lp[0 * 64] = t.r0; lp[1 * 64] = t.r1; lp[2 * 64] = t.r2; lp[3 * 64] = t.r3;
    lp[4 * 64] = t.r4; lp[5 * 64] = t.r5; lp[6 * 64] = t.r6; lp[7 * 64] = t.r7;
    __syncthreads();

    if (ps == 0) {
#pragma unroll
        for (int p = 1; p < 8; ++p) {
            const float* rp = lds + p * TOPK * 64 + c;
            t8_ins(t, rp[0 * 64]); t8_ins(t, rp[1 * 64]);
            t8_ins(t, rp[2 * 64]); t8_ins(t, rp[3 * 64]);
            t8_ins(t, rp[4 * 64]); t8_ins(t, rp[5 * 64]);
            t8_ins(t, rp[6 * 64]); t8_ins(t, rp[7 * 64]);
        }
        float* op = out + (size_t)b * (TOPK * DD) + d;
        op[0 * DD] = t.r0; op[1 * DD] = t.r1; op[2 * DD] = t.r2; op[3 * DD] = t.r3;
        op[4 * DD] = t.r4; op[5 * DD] = t.r5; op[6 * DD] = t.r6; op[7 * DD] = t.r7;
    }
}

// No-workspace fallback (only if ws_size < 32 MB): thread = (b, d) column.
__global__ __launch_bounds__(256) void topk_fallback(
    const float* __restrict__ x, const int* __restrict__ mask,
    float* __restrict__ out) {
    const int b = blockIdx.x;
    const int d = threadIdx.x;
    const int* mrow = mask + b * LL;
    const int len = mask_lower_bound(mrow, 0, LL);

    Top8 t;
    t8_init(t);
    const float* xp = x + (size_t)b * LL * DD + d;
    for (int l = 0; l < len; ++l) t8_ins(t, xp[(size_t)l * DD]);

    float* op = out + (size_t)b * (TOPK * DD) + d;
    op[0 * DD] = t.r0; op[1 * DD] = t.r1; op[2 * DD] = t.r2; op[3 * DD] = t.r3;
    op[4 * DD] = t.r4; op[5 * DD] = t.r5; op[6 * DD] = t.r6; op[7 * DD] = t.r7;
}

extern "C" void kernel_launch(void* const* d_in, const int* in_sizes, int n_in,
                              void* d_out, int out_size, void* d_ws, size_t ws_size,
                              hipStream_t stream) {
    const float* x = (const float*)d_in[0];
    const int* mask = (const int*)d_in[1];
    float* out = (float*)d_out;

    const size_t ws_need = (size_t)BB * NC * TOPK * DD * 4;   // 32 MB
    if (ws_size >= ws_need) {
        float* ws = (float*)d_ws;
        dim3 g1(BB, NC / 4);        // wave per chunk, 4 chunks per block
        topk_pass1<<<g1, 256, 0, stream>>>(x, mask, ws);
        dim3 g2(BB, 4);
        topk_pass2<<<g2, 512, 0, stream>>>(ws, mask, out);
    } else {
        topk_fallback<<<BB, 256, 0, stream>>>(x, mask, out);
    }
}

// Round 3
// 344.021 us; speedup vs baseline: 1.0466x; 1.0466x over previous
//
#include <hip/hip_runtime.h>
#include <cfloat>

// TopKPooling: per (b, d) channel, top-8 over L with monotone padding mask.
// x: (B=32, L=8192, D=256) f32, x_mask: (B, L) i32 (1 = padded, monotone 0->1)
// out: (B, 8*D) f32, out[b][k*D + d] = k-th largest of valid x[b][:,d].
//
// R3 changes vs R2 (theory: pass1 latency-bound — only ~2 loads in flight
// per wave):
//  - 4-deep row pipeline: 4 independent float4 loads issued per iteration
//    (16 KB/wave in flight, 64 KB/CU at 16 waves/CU) before any insert.
//  - non-temporal loads for x (streamed once, 256 MB -> no L2 reuse;
//    keeps mask + ws resident in L2).

#define TOPK 8
#define BB 32
#define LL 8192
#define DD 256
#define CL 64           // L-rows per wave-chunk
#define NC (LL / CL)    // 128 chunks per batch row

typedef float v4f __attribute__((ext_vector_type(4)));

struct Top8 { float r0, r1, r2, r3, r4, r5, r6, r7; };

#define CMPX(a, b) { float _hi = fmaxf(a, b); float _lo = fminf(a, b); (a) = _hi; (b) = _lo; }

__device__ __forceinline__ void t8_init(Top8& t) {
    t.r0 = t.r1 = t.r2 = t.r3 = t.r4 = t.r5 = t.r6 = t.r7 = -FLT_MAX;
}

// r0>=r1>=...>=r7 descending. One max + 7 compare-exchanges, branchless.
__device__ __forceinline__ void t8_ins(Top8& t, float v) {
    t.r7 = fmaxf(t.r7, v);
    CMPX(t.r6, t.r7); CMPX(t.r5, t.r6); CMPX(t.r4, t.r5); CMPX(t.r3, t.r4);
    CMPX(t.r2, t.r3); CMPX(t.r1, t.r2); CMPX(t.r0, t.r1);
}

// first index where mrow[i] != 0, assuming monotone 0->1; returns hi0 if none
__device__ __forceinline__ int mask_lower_bound(const int* mrow, int lo0, int hi0) {
    int lo = lo0, hi = hi0;
    while (lo < hi) {
        int mid = (lo + hi) >> 1;
        if (mrow[mid]) hi = mid; else lo = mid + 1;
    }
    return lo;
}

__global__ __launch_bounds__(256, 4) void topk_pass1(
    const float* __restrict__ x, const int* __restrict__ mask,
    float* __restrict__ ws) {
    const int b = blockIdx.x;
    const int lane = threadIdx.x & 63;
    const int wv = threadIdx.x >> 6;            // 0..3
    const int chunk = blockIdx.y * 4 + wv;      // 0..127
    const int l0 = chunk * CL;
    const int* mrow = mask + b * LL;

    if (mrow[l0]) return;   // fully padded chunk: pass2 will not read its slot

    int nvalid;
    if (!mrow[l0 + CL - 1]) {
        nvalid = CL;
    } else {
        nvalid = mask_lower_bound(mrow, l0 + 1, l0 + CL - 1) - l0;  // >=1
    }

    Top8 t0, t1, t2, t3;
    t8_init(t0); t8_init(t1); t8_init(t2); t8_init(t3);

    // lane owns channels lane*4 .. lane*4+3; row stride = 64 float4s
    const v4f* xp = (const v4f*)(x + ((size_t)b * LL + l0) * DD) + lane;

#define INS4(v) { t8_ins(t0, (v).x); t8_ins(t1, (v).y); t8_ins(t2, (v).z); t8_ins(t3, (v).w); }

    const int rem_start = nvalid & ~3;
    if (nvalid >= 4) {
        // 4-deep software pipeline: 4 independent loads in flight per wave
        v4f a = __builtin_nontemporal_load(xp + 0 * (DD / 4));
        v4f b4 = __builtin_nontemporal_load(xp + 1 * (DD / 4));
        v4f c = __builtin_nontemporal_load(xp + 2 * (DD / 4));
        v4f e = __builtin_nontemporal_load(xp + 3 * (DD / 4));
        for (int l = 4; l + 4 <= nvalid; l += 4) {
            v4f na = __builtin_nontemporal_load(xp + (size_t)(l + 0) * (DD / 4));
            v4f nb = __builtin_nontemporal_load(xp + (size_t)(l + 1) * (DD / 4));
            v4f nc = __builtin_nontemporal_load(xp + (size_t)(l + 2) * (DD / 4));
            v4f ne = __builtin_nontemporal_load(xp + (size_t)(l + 3) * (DD / 4));
            INS4(a); INS4(b4); INS4(c); INS4(e);
            a = na; b4 = nb; c = nc; e = ne;
        }
        INS4(a); INS4(b4); INS4(c); INS4(e);
    }
    for (int l = rem_start; l < nvalid; ++l) {
        v4f v = __builtin_nontemporal_load(xp + (size_t)l * (DD / 4));
        INS4(v);
    }
#undef INS4

    // ws[b][chunk][k][ch]: per k, lanes store float4 at consecutive channels
    float4* wp = (float4*)(ws + ((size_t)(b * NC + chunk) * TOPK) * DD) + lane;
    wp[0 * (DD / 4)] = make_float4(t0.r0, t1.r0, t2.r0, t3.r0);
    wp[1 * (DD / 4)] = make_float4(t0.r1, t1.r1, t2.r1, t3.r1);
    wp[2 * (DD / 4)] = make_float4(t0.r2, t1.r2, t2.r2, t3.r2);
    wp[3 * (DD / 4)] = make_float4(t0.r3, t1.r3, t2.r3, t3.r3);
    wp[4 * (DD / 4)] = make_float4(t0.r4, t1.r4, t2.r4, t3.r4);
    wp[5 * (DD / 4)] = make_float4(t0.r5, t1.r5, t2.r5, t3.r5);
    wp[6 * (DD / 4)] = make_float4(t0.r6, t1.r6, t2.r6, t3.r6);
    wp[7 * (DD / 4)] = make_float4(t0.r7, t1.r7, t2.r7, t3.r7);
}

__global__ __launch_bounds__(512) void topk_pass2(
    const float* __restrict__ ws, const int* __restrict__ mask,
    float* __restrict__ out) {
    __shared__ float lds[8 * TOPK * 64];        // 16 KB
    const int b = blockIdx.x;
    const int q = blockIdx.y;                   // channel group 0..3
    const int c = threadIdx.x & 63;
    const int ps = threadIdx.x >> 6;            // 0..7 list-split groups
    const int d = q * 64 + c;
    const int* mrow = mask + b * LL;

    // length of valid region (uniform across block; lengths >= 8 guaranteed)
    const int len = mask_lower_bound(mrow, 0, LL);
    const int nvc = (len + CL - 1) / CL;        // chunks actually written

    Top8 t;
    t8_init(t);
    for (int j = ps; j < nvc; j += 8) {
        const float* wp = ws + ((size_t)(b * NC + j) * TOPK) * DD + d;
        t8_ins(t, wp[0 * DD]); t8_ins(t, wp[1 * DD]);
        t8_ins(t, wp[2 * DD]); t8_ins(t, wp[3 * DD]);
        t8_ins(t, wp[4 * DD]); t8_ins(t, wp[5 * DD]);
        t8_ins(t, wp[6 * DD]); t8_ins(t, wp[7 * DD]);
    }

    float* lp = lds + ps * TOPK * 64 + c;
    lp[0 * 64] = t.r0; lp[1 * 64] = t.r1; lp[2 * 64] = t.r2; lp[3 * 64] = t.r3;
    lp[4 * 64] = t.r4; lp[5 * 64] = t.r5; lp[6 * 64] = t.r6; lp[7 * 64] = t.r7;
    __syncthreads();

    if (ps == 0) {
#pragma unroll
        for (int p = 1; p < 8; ++p) {
            const float* rp = lds + p * TOPK * 64 + c;
            t8_ins(t, rp[0 * 64]); t8_ins(t, rp[1 * 64]);
            t8_ins(t, rp[2 * 64]); t8_ins(t, rp[3 * 64]);
            t8_ins(t, rp[4 * 64]); t8_ins(t, rp[5 * 64]);
            t8_ins(t, rp[6 * 64]); t8_ins(t, rp[7 * 64]);
        }
        float* op = out + (size_t)b * (TOPK * DD) + d;
        op[0 * DD] = t.r0; op[1 * DD] = t.r1; op[2 * DD] = t.r2; op[3 * DD] = t.r3;
        op[4 * DD] = t.r4; op[5 * DD] = t.r5; op[6 * DD] = t.r6; op[7 * DD] = t.r7;
    }
}

// No-workspace fallback (only if ws_size < 32 MB): thread = (b, d) column.
__global__ __launch_bounds__(256) void topk_fallback(
    const float* __restrict__ x, const int* __restrict__ mask,
    float* __restrict__ out) {
    const int b = blockIdx.x;
    const int d = threadIdx.x;
    const int* mrow = mask + b * LL;
    const int len = mask_lower_bound(mrow, 0, LL);

    Top8 t;
    t8_init(t);
    const float* xp = x + (size_t)b * LL * DD + d;
    for (int l = 0; l < len; ++l) t8_ins(t, xp[(size_t)l * DD]);

    float* op = out + (size_t)b * (TOPK * DD) + d;
    op[0 * DD] = t.r0; op[1 * DD] = t.r1; op[2 * DD] = t.r2; op[3 * DD] = t.r3;
    op[4 * DD] = t.r4; op[5 * DD] = t.r5; op[6 * DD] = t.r6; op[7 * DD] = t.r7;
}

extern "C" void kernel_launch(void* const* d_in, const int* in_sizes, int n_in,
                              void* d_out, int out_size, void* d_ws, size_t ws_size,
                              hipStream_t stream) {
    const float* x = (const float*)d_in[0];
    const int* mask = (const int*)d_in[1];
    float* out = (float*)d_out;

    const size_t ws_need = (size_t)BB * NC * TOPK * DD * 4;   // 32 MB
    if (ws_size >= ws_need) {
        float* ws = (float*)d_ws;
        dim3 g1(BB, NC / 4);        // wave per chunk, 4 chunks per block
        topk_pass1<<<g1, 256, 0, stream>>>(x, mask, ws);
        dim3 g2(BB, 4);
        topk_pass2<<<g2, 512, 0, stream>>>(ws, mask, out);
    } else {
        topk_fallback<<<BB, 256, 0, stream>>>(x, mask, out);
    }
}